// Round 3
// baseline (307.718 us; speedup 1.0000x reference)
//
#include <hip/hip_runtime.h>
#include <hip/hip_bf16.h>
#include <math.h>

#define B_   8192
#define F_   48
#define T_   512
#define L_   8
#define NBLK 256
#define THR  512
#define NW   8           // waves per block
#define RPB  32          // rows per block
#define HST  520         // H LDS row stride in shorts (1040B; 65 uint4)
#define ZS   52          // z LDS row stride in floats
#define LINE 32          // dwords per 128B line
#define EVT_DW (NBLK * LINE)   // one 128B line per block per event
#define NEVT 8
#define SYNC_DW (NEVT * EVT_DW)

typedef unsigned short ushort_t;
typedef unsigned int   uint_t;
typedef __attribute__((ext_vector_type(8))) short short8;
typedef __attribute__((ext_vector_type(4))) float f32x4;

#define MFMA(a,b,c) __builtin_amdgcn_mfma_f32_16x16x32_bf16(a,b,c,0,0,0)

__device__ inline ushort_t f2bf(float x) {
    __hip_bfloat16 h = __float2bfloat16(x);
    return *reinterpret_cast<ushort_t*>(&h);
}
__device__ inline short8 negbf(short8 v) {
    short8 r;
    #pragma unroll
    for (int i = 0; i < 8; ++i) r[i] = v[i] ^ (short)0x8000;
    return r;
}
__device__ inline short8 pack8(float4 a, float4 b) {
    short8 r;
    r[0]=(short)f2bf(a.x); r[1]=(short)f2bf(a.y); r[2]=(short)f2bf(a.z); r[3]=(short)f2bf(a.w);
    r[4]=(short)f2bf(b.x); r[5]=(short)f2bf(b.y); r[6]=(short)f2bf(b.z); r[7]=(short)f2bf(b.w);
    return r;
}

__device__ inline float aload(const float* p) {
    return __hip_atomic_load(p, __ATOMIC_RELAXED, __HIP_MEMORY_SCOPE_AGENT);
}
__device__ inline void astore(float* p, float v) {
    __hip_atomic_store(p, v, __ATOMIC_RELAXED, __HIP_MEMORY_SCOPE_AGENT);
}

// --- store/gather broadcast sync -----------------------------------------
// Event = NBLK lines of 128B. Line b: dword0 = flag, dwords1..8 = values.
// Publisher (tid 0): relaxed-store values, release-store flag. No RMW.
// Waiter: wave 0 gathers all flags wave-wide; waves 0..nv-1 gather+reduce
// one value each in parallel. Results land in red[0..nv-1].
__device__ inline void publish(float* evtbase, int blk, const float* v, int nv) {
    float* line = evtbase + (size_t)blk * LINE;
    #pragma unroll
    for (int j = 0; j < 8; ++j)
        if (j < nv) astore(line + 1 + j, v[j]);
    __hip_atomic_store((uint_t*)line, 1u, __ATOMIC_RELEASE, __HIP_MEMORY_SCOPE_AGENT);
}

__device__ inline void evt_wait(float* evtbase, int wave, int lane, int nv, float* red) {
    if (wave == 0) {
        uint_t* f0 = (uint_t*)evtbase;
        for (;;) {
            bool ok = true;
            #pragma unroll
            for (int g = 0; g < NBLK / 64; ++g) {
                uint_t fl = __hip_atomic_load(f0 + (size_t)(g * 64 + lane) * LINE,
                                              __ATOMIC_RELAXED, __HIP_MEMORY_SCOPE_AGENT);
                ok = ok && (fl != 0u);
            }
            if (__all(ok)) break;
            __builtin_amdgcn_s_sleep(1);
        }
    }
    __syncthreads();
    if (wave < nv) {
        float s = 0.f;
        #pragma unroll
        for (int g = 0; g < NBLK / 64; ++g)
            s += aload(evtbase + (size_t)(g * 64 + lane) * LINE + 1 + wave);
        #pragma unroll
        for (int o = 32; o > 0; o >>= 1) s += __shfl_xor(s, o, 64);
        if (lane == 0) red[wave] = s;
    }
    __syncthreads();
}

// ---------- prep: frag-linear bf16 layouts + zero sync region ----------
__global__ __launch_bounds__(256) void k_pre(
    const float* __restrict__ Ar, const float* __restrict__ Ai,
    const float* __restrict__ Dr, const float* __restrict__ Di,
    ushort_t* __restrict__ Afr, ushort_t* __restrict__ Afi,
    ushort_t* __restrict__ Atr, ushort_t* __restrict__ Ati,
    ushort_t* __restrict__ Dfr, ushort_t* __restrict__ Dfi,
    uint_t* __restrict__ syncbuf)
{
    const int gt = blockIdx.x * 256 + threadIdx.x;
    const int gs = gridDim.x * 256;
    for (int idx = gt; idx < SYNC_DW; idx += gs) syncbuf[idx] = 0u;
    for (int idx = gt; idx < L_ * 32768; idx += gs) {
        int j = idx & 7, rest = idx >> 3;
        int mm = rest & 15; rest >>= 4;
        int qq = rest & 3;  rest >>= 2;
        int k2 = rest & 1;  rest >>= 1;
        int tile = rest & 31;
        int l = rest >> 5;
        int t = tile * 16 + mm, k = k2 * 32 + qq * 8 + j;
        float vr = 0.f, vi = 0.f;
        if (k < 48) { int g = l * 24576 + t * 48 + k; vr = Ar[g]; vi = Ai[g]; }
        Afr[idx] = f2bf(vr); Afi[idx] = f2bf(vi);
    }
    for (int idx = gt; idx < L_ * 24576; idx += gs) {
        int j = idx & 7, rest = idx >> 3;
        int mm = rest & 15; rest >>= 4;
        int qq = rest & 3;  rest >>= 2;
        int ks = rest & 15; rest >>= 4;
        int ft = rest % 3;
        int l = rest / 3;
        int f = ft * 16 + mm, k = ks * 32 + qq * 8 + j;
        int g = l * 24576 + k * 48 + f;
        Atr[idx] = f2bf(Ar[g]); Ati[idx] = f2bf(Ai[g]);
    }
    for (int idx = gt; idx < 24576; idx += gs) {
        int j = idx & 7, rest = idx >> 3;
        int mm = rest & 15; rest >>= 4;
        int qq = rest & 3;  rest >>= 2;
        int ks = rest & 15;
        int ft = rest >> 4;
        int f = ft * 16 + mm, k = ks * 32 + qq * 8 + j;
        Dfr[idx] = f2bf(Dr[k * 48 + f]); Dfi[idx] = f2bf(Di[k * 48 + f]);
    }
}

// ---------- persistent cooperative kernel ----------
// ONE global sync per layer: payload {cnt_re, cnt_im, S1..S6} where
// S = quadratic partials of z_new in terms of b:  a = u - h,
// ||z_new||^2 = S(a^2) + 2b S(a z) + b^2 S(z^2)  per re/im component.
// After the wait every block derives b_l AND sigma_{l+1} locally.
__global__ __launch_bounds__(THR, 2) void k_lamp(
    const float* __restrict__ u,
    const ushort_t* __restrict__ Afr, const ushort_t* __restrict__ Afi,
    const ushort_t* __restrict__ Atr, const ushort_t* __restrict__ Ati,
    const ushort_t* __restrict__ Dfr, const ushort_t* __restrict__ Dfi,
    const float* __restrict__ th,
    uint_t* syncbuf,
    float* __restrict__ out)
{
    extern __shared__ char dyn[];
    float*    pR   = (float*)dyn;                  // [8][3][16][17] 26112 B
    float*    pI   = pR + 8 * 3 * 16 * 17;         // 26112 B
    float*    zreL = pI + 8 * 3 * 16 * 17;         // 6656 B
    float*    zimL = zreL + RPB * ZS;              // 6656 B
    float*    red  = zimL + RPB * ZS;              // 512 B (128 floats)
    ushort_t* HreL = (ushort_t*)(red + 128);       // 33280 B
    ushort_t* HimL = HreL + RPB * HST;             // 33280 B  => 132608 B

    float* evt = (float*)syncbuf;                  // event e: evt + e*EVT_DW

    const int tid = threadIdx.x, blk = blockIdx.x;
    const int row0 = blk * RPB;
    const int wave = tid >> 6, lane = tid & 63;
    const int quad = lane >> 4, m = lane & 15;
    const int rows16 = (wave >> 2) * 16;           // fwd: which 16-row tile
    const int rt = wave >> 2, kq = wave & 3;       // bwd: row-tile / K-quarter
    const float2* u2 = (const float2*)u;

    // persistent H fragments (f32): H[ct][reg] at (row=rows16+quad*4+reg, col=tile*16+m)
    f32x4 hR[8], hI[8];
    #pragma unroll
    for (int ct = 0; ct < 8; ++ct) { hR[ct] = (f32x4){0,0,0,0}; hI[ct] = (f32x4){0,0,0,0}; }

    // prologue: u -> z LDS, ||u||^2 partial -> event 0
    float acc = 0.f;
    #pragma unroll
    for (int k3 = 0; k3 < 3; ++k3) {
        int j = tid + k3 * THR;
        int r = j / 48, c = j - r * 48;
        float2 v = u2[(row0 + r) * 48 + c];
        zreL[r * ZS + c] = v.x; zimL[r * ZS + c] = v.y;
        acc += v.x * v.x + v.y * v.y;
    }
    #pragma unroll
    for (int o = 32; o > 0; o >>= 1) acc += __shfl_xor(acc, o, 64);
    __syncthreads();                         // publishes z LDS
    if (lane == 0) red[16 + wave] = acc;
    __syncthreads();
    if (tid == 0) {
        float t = 0.f;
        #pragma unroll
        for (int w = 0; w < NW; ++w) t += red[16 + w];
        publish(evt, blk, &t, 1);
    }

    float lam = 0.f;
    for (int l = 0; l < L_; ++l) {
        const float th1 = th[l * 3 + 1];

        // z A-frags from LDS fp32 (K=48 padded to 64)
        const float* zpr = zreL + (rows16 + m) * ZS;
        const float* zpi = zimL + (rows16 + m) * ZS;
        short8 zr0 = pack8(*(const float4*)(zpr + quad * 8), *(const float4*)(zpr + quad * 8 + 4));
        short8 zi0 = pack8(*(const float4*)(zpi + quad * 8), *(const float4*)(zpi + quad * 8 + 4));
        short8 zr1 = {0,0,0,0,0,0,0,0}, zi1 = {0,0,0,0,0,0,0,0};
        if (quad < 2) {
            zr1 = pack8(*(const float4*)(zpr + 32 + quad * 8), *(const float4*)(zpr + 36 + quad * 8));
            zi1 = pack8(*(const float4*)(zpi + 32 + quad * 8), *(const float4*)(zpi + 36 + quad * 8));
        }
        short8 zin0 = negbf(zi0), zin1 = negbf(zi1);

        // forward GEMM accumulating straight onto H_old (R = H + Z in registers)
        const ushort_t* Aflr = Afr + (size_t)l * 32768;
        const ushort_t* Afli = Afi + (size_t)l * 32768;
        #pragma unroll
        for (int ct = 0; ct < 8; ++ct) {
            const int tile = (wave & 3) * 8 + ct;
            const ushort_t* rp = Aflr + (size_t)(tile * 2) * 512 + lane * 8;
            const ushort_t* ip = Afli + (size_t)(tile * 2) * 512 + lane * 8;
            short8 ar0 = *(const short8*)rp;
            short8 ar1 = *(const short8*)(rp + 512);
            short8 ai0 = *(const short8*)ip;
            short8 ai1 = *(const short8*)(ip + 512);
            hR[ct] = MFMA(zr0, ar0, hR[ct]);
            hR[ct] = MFMA(zr1, ar1, hR[ct]);
            hR[ct] = MFMA(zin0, ai0, hR[ct]);
            hR[ct] = MFMA(zin1, ai1, hR[ct]);
            hI[ct] = MFMA(zr0, ai0, hI[ct]);
            hI[ct] = MFMA(zr1, ai1, hI[ct]);
            hI[ct] = MFMA(zi0, ar0, hI[ct]);
            hI[ct] = MFMA(zi1, ar1, hI[ct]);
        }

        // sigma_0 event hides behind the first fwd GEMM; later layers have
        // lam already computed locally from the previous layer's event.
        if (l == 0) {
            evt_wait(evt, wave, lane, 1, red);
            lam = th[0] * sqrtf(red[0] * (1.0f / 48.0f));
        }

        // activation on registers: Hn = act(R); store Hn bf16 to LDS for bwd GEMM
        float cr = 0.f, ci = 0.f;
        #pragma unroll
        for (int ct = 0; ct < 8; ++ct) {
            const int t = ((wave & 3) * 8 + ct) * 16 + m;
            #pragma unroll
            for (int reg = 0; reg < 4; ++reg) {
                const int lr = rows16 + quad * 4 + reg;
                float Rr = hR[ct][reg], Ri = hI[ct][reg];
                float mr = fabsf(Rr), mi = fabsf(Ri);
                float fr = th1 * copysignf(fmaxf(mr - lam, 0.f), Rr);
                float fi = th1 * copysignf(fmaxf(mi - lam, 0.f), Ri);
                cr += (mr > lam) ? 1.f : 0.f;
                ci += (mi > lam) ? 1.f : 0.f;
                hR[ct][reg] = fr; hI[ct][reg] = fi;
                HreL[lr * HST + t] = f2bf(fr);
                HimL[lr * HST + t] = f2bf(fi);
            }
        }

        if (l == L_ - 1) { __syncthreads(); break; }   // publish Hn for final GEMM
        __syncthreads();                               // publish Hn for bwd GEMM

        // backward GEMM: h = Hn @ A; wave (rt,kq) does rows rt*16..+16, K quarter kq
        const ushort_t* Atlr = Atr + (size_t)l * 24576;
        const ushort_t* Atli = Ati + (size_t)l * 24576;
        f32x4 aR[3], aI[3];
        #pragma unroll
        for (int q = 0; q < 3; ++q) { aR[q] = (f32x4){0,0,0,0}; aI[q] = (f32x4){0,0,0,0}; }
        #pragma unroll
        for (int ks = 0; ks < 4; ++ks) {
            const int ksa = kq * 4 + ks;
            const int k0 = ksa * 32 + quad * 8;
            short8 hr = *(const short8*)&HreL[(rt * 16 + m) * HST + k0];
            short8 hi = *(const short8*)&HimL[(rt * 16 + m) * HST + k0];
            short8 hin = negbf(hi);
            #pragma unroll
            for (int ft = 0; ft < 3; ++ft) {
                short8 br = *(const short8*)(Atlr + (size_t)((ft * 16 + ksa) * 64 + lane) * 8);
                short8 bi = *(const short8*)(Atli + (size_t)((ft * 16 + ksa) * 64 + lane) * 8);
                aR[ft] = MFMA(hr, br, aR[ft]);
                aR[ft] = MFMA(hin, bi, aR[ft]);
                aI[ft] = MFMA(hr, bi, aI[ft]);
                aI[ft] = MFMA(hi, br, aI[ft]);
            }
        }
        #pragma unroll
        for (int ft = 0; ft < 3; ++ft) {
            #pragma unroll
            for (int reg = 0; reg < 4; ++reg) {
                pR[((wave * 3 + ft) * 16 + quad * 4 + reg) * 17 + m] = aR[ft][reg];
                pI[((wave * 3 + ft) * 16 + quad * 4 + reg) * 17 + m] = aI[ft][reg];
            }
        }
        __syncthreads();                               // publish pR/pI

        // quadratic partials: a = u - h, vs z_old (kept in registers for z write)
        float aRe[3], aIm[3], zR3[3], zI3[3];
        float S1 = 0.f, S2 = 0.f, S3 = 0.f, S4 = 0.f, S5 = 0.f, S6 = 0.f;
        #pragma unroll
        for (int k3 = 0; k3 < 3; ++k3) {
            int j = tid + k3 * THR;
            int r = j / 48, f = j - r * 48;
            int rt2 = r >> 4, lr = r & 15, ft = f >> 4, c = f & 15;
            float hRv = 0.f, hIv = 0.f;
            #pragma unroll
            for (int q = 0; q < 4; ++q) {
                hRv += pR[(((rt2 * 4 + q) * 3 + ft) * 16 + lr) * 17 + c];
                hIv += pI[(((rt2 * 4 + q) * 3 + ft) * 16 + lr) * 17 + c];
            }
            float2 uv = u2[(row0 + r) * 48 + f];
            float zr = zreL[r * ZS + f], zi = zimL[r * ZS + f];
            float ar = uv.x - hRv, ai = uv.y - hIv;
            aRe[k3] = ar; aIm[k3] = ai; zR3[k3] = zr; zI3[k3] = zi;
            S1 += ar * ar; S2 += ar * zr; S3 += zr * zr;
            S4 += ai * ai; S5 += ai * zi; S6 += zi * zi;
        }

        // block-reduce 8 values and publish event l+1
        float v8[8] = {cr, ci, S1, S2, S3, S4, S5, S6};
        #pragma unroll
        for (int j = 0; j < 8; ++j) {
            #pragma unroll
            for (int o = 32; o > 0; o >>= 1) v8[j] += __shfl_xor(v8[j], o, 64);
        }
        if (lane == 0) {
            #pragma unroll
            for (int j = 0; j < 8; ++j) red[16 + wave * 8 + j] = v8[j];
        }
        __syncthreads();
        if (tid == 0) {
            float o8[8];
            #pragma unroll
            for (int j = 0; j < 8; ++j) {
                float s = 0.f;
                #pragma unroll
                for (int w = 0; w < NW; ++w) s += red[16 + w * 8 + j];
                o8[j] = s;
            }
            publish(evt + (size_t)(l + 1) * EVT_DW, blk, o8, 8);
        }

        // the ONE exposed global wait of this layer
        evt_wait(evt + (size_t)(l + 1) * EVT_DW, wave, lane, 8, red);
        const float CR = red[0], CI = red[1];
        const float G1 = red[2], G2 = red[3], G3 = red[4];
        const float G4 = red[5], G5 = red[6], G6 = red[7];
        const float bre = th1 * CR * (1.0f / 48.0f);
        const float bim = th1 * CI * (1.0f / 48.0f);
        const float sig2 = G1 + 2.f * bre * G2 + bre * bre * G3
                         + G4 + 2.f * bim * G5 + bim * bim * G6;
        lam = th[(l + 1) * 3] * sqrtf(sig2 * (1.0f / 48.0f));

        // z write from cached registers (no global data needed)
        #pragma unroll
        for (int k3 = 0; k3 < 3; ++k3) {
            int j = tid + k3 * THR;
            int r = j / 48, f = j - r * 48;
            zreL[r * ZS + f] = aRe[k3] + bre * zR3[k3];
            zimL[r * ZS + f] = aIm[k3] + bim * zI3[k3];
        }
        __syncthreads();                 // z published for next fwd GEMM
    }

    // final: out = Hn(LDS) @ DFT  (wave (rt,kq), K-split, LDS combine)
    f32x4 fR[3], fI[3];
    #pragma unroll
    for (int q = 0; q < 3; ++q) { fR[q] = (f32x4){0,0,0,0}; fI[q] = (f32x4){0,0,0,0}; }
    #pragma unroll
    for (int ks = 0; ks < 4; ++ks) {
        const int ksa = kq * 4 + ks;
        const int k0 = ksa * 32 + quad * 8;
        short8 hr = *(const short8*)&HreL[(rt * 16 + m) * HST + k0];
        short8 hi = *(const short8*)&HimL[(rt * 16 + m) * HST + k0];
        short8 hin = negbf(hi);
        #pragma unroll
        for (int ft = 0; ft < 3; ++ft) {
            short8 br = *(const short8*)(Dfr + (size_t)((ft * 16 + ksa) * 64 + lane) * 8);
            short8 bi = *(const short8*)(Dfi + (size_t)((ft * 16 + ksa) * 64 + lane) * 8);
            fR[ft] = MFMA(hr, br, fR[ft]);
            fR[ft] = MFMA(hin, bi, fR[ft]);
            fI[ft] = MFMA(hr, bi, fI[ft]);
            fI[ft] = MFMA(hi, br, fI[ft]);
        }
    }
    #pragma unroll
    for (int ft = 0; ft < 3; ++ft) {
        #pragma unroll
        for (int reg = 0; reg < 4; ++reg) {
            pR[((wave * 3 + ft) * 16 + quad * 4 + reg) * 17 + m] = fR[ft][reg];
            pI[((wave * 3 + ft) * 16 + quad * 4 + reg) * 17 + m] = fI[ft][reg];
        }
    }
    __syncthreads();
    float2* out2 = (float2*)out;
    #pragma unroll
    for (int k3 = 0; k3 < 3; ++k3) {
        int j = tid + k3 * THR;
        int r = j / 48, f = j - r * 48;
        int rt2 = r >> 4, lr = r & 15, ft = f >> 4, c = f & 15;
        float hRv = 0.f, hIv = 0.f;
        #pragma unroll
        for (int q = 0; q < 4; ++q) {
            hRv += pR[(((rt2 * 4 + q) * 3 + ft) * 16 + lr) * 17 + c];
            hIv += pI[(((rt2 * 4 + q) * 3 + ft) * 16 + lr) * 17 + c];
        }
        out2[(row0 + r) * 48 + f] = make_float2(hRv, hIv);
    }
}

extern "C" void kernel_launch(void* const* d_in, const int* in_sizes, int n_in,
                              void* d_out, int out_size, void* d_ws, size_t ws_size,
                              hipStream_t stream) {
    (void)in_sizes; (void)n_in; (void)out_size; (void)ws_size;
    const float* u  = (const float*)d_in[0];
    const float* Ar = (const float*)d_in[1];
    const float* Ai = (const float*)d_in[2];
    const float* th = (const float*)d_in[3];
    const float* Dr = (const float*)d_in[4];
    const float* Di = (const float*)d_in[5];
    float* out = (float*)d_out;

    char* p = (char*)d_ws;
    auto alloc = [&](size_t bytes) -> char* {
        char* r = p;
        p += (bytes + 255) & ~(size_t)255;
        return r;
    };
    uint_t*   syncbuf = (uint_t*)alloc((size_t)SYNC_DW * 4);
    ushort_t* Afr = (ushort_t*)alloc((size_t)L_ * 32768 * 2);
    ushort_t* Afi = (ushort_t*)alloc((size_t)L_ * 32768 * 2);
    ushort_t* Atr = (ushort_t*)alloc((size_t)L_ * 24576 * 2);
    ushort_t* Ati = (ushort_t*)alloc((size_t)L_ * 24576 * 2);
    ushort_t* Dfr = (ushort_t*)alloc((size_t)24576 * 2);
    ushort_t* Dfi = (ushort_t*)alloc((size_t)24576 * 2);

    k_pre<<<1024, 256, 0, stream>>>(Ar, Ai, Dr, Di, Afr, Afi, Atr, Ati, Dfr, Dfi, syncbuf);

    const uint_t lds_bytes = 132608;
    hipFuncSetAttribute((const void*)k_lamp,
                        hipFuncAttributeMaxDynamicSharedMemorySize, (int)lds_bytes);
    void* args[] = { (void*)&u, (void*)&Afr, (void*)&Afi, (void*)&Atr, (void*)&Ati,
                     (void*)&Dfr, (void*)&Dfi, (void*)&th,
                     (void*)&syncbuf, (void*)&out };
    hipLaunchCooperativeKernel((void*)k_lamp, dim3(NBLK), dim3(THR), args,
                               lds_bytes, stream);
}

// Round 5
// 286.311 us; speedup vs baseline: 1.0748x; 1.0748x over previous
//
#include <hip/hip_runtime.h>
#include <hip/hip_bf16.h>
#include <math.h>

#define B_   8192
#define F_   48
#define T_   512
#define L_   8
#define NBLK 256
#define THR  512
#define NW   8           // waves per block
#define RPB  32          // rows per block
#define HST  520         // H LDS row stride in shorts (1040B; 65 uint4)
#define ZS   52          // z LDS row stride in floats
#define LINE 32          // dwords per 128B line
#define EVT_LINES 32     // 8 values x 4 sublines, one line each
#define NEVT 8
#define SYNC_DW ((1 + NEVT * EVT_LINES) * LINE)   // counter line + events

typedef unsigned short ushort_t;
typedef unsigned int   uint_t;
typedef __attribute__((ext_vector_type(8))) short short8;
typedef __attribute__((ext_vector_type(4))) float f32x4;

#define MFMA(a,b,c) __builtin_amdgcn_mfma_f32_16x16x32_bf16(a,b,c,0,0,0)

__device__ inline ushort_t f2bf(float x) {
    __hip_bfloat16 h = __float2bfloat16(x);
    return *reinterpret_cast<ushort_t*>(&h);
}
__device__ inline short8 negbf(short8 v) {
    short8 r;
    #pragma unroll
    for (int i = 0; i < 8; ++i) r[i] = v[i] ^ (short)0x8000;
    return r;
}
__device__ inline short8 pack8(float4 a, float4 b) {
    short8 r;
    r[0]=(short)f2bf(a.x); r[1]=(short)f2bf(a.y); r[2]=(short)f2bf(a.z); r[3]=(short)f2bf(a.w);
    r[4]=(short)f2bf(b.x); r[5]=(short)f2bf(b.y); r[6]=(short)f2bf(b.z); r[7]=(short)f2bf(b.w);
    return r;
}

__device__ inline float aload(const float* p) {
    return __hip_atomic_load(p, __ATOMIC_RELAXED, __HIP_MEMORY_SCOPE_AGENT);
}
__device__ inline void afadd(float* p, float v) {
    (void)__hip_atomic_fetch_add(p, v, __ATOMIC_RELAXED, __HIP_MEMORY_SCOPE_AGENT);
}

// --- R1-style sync transport: fire-and-forget adds + single counter -------
// Event e: vbase = sync + (1 + e*EVT_LINES)*LINE. Value j, subline q (blk&3)
// at vbase + (j*4+q)*LINE. Counter: sync dword 0, cumulative across events.
// publish/consume are called by tid 0 only.
template<int NV>
__device__ inline void evt_publish(float* vbase, uint_t* cnt, int blk, const float* v) {
    #pragma unroll
    for (int j = 0; j < NV; ++j)
        afadd(vbase + (j * 4 + (blk & 3)) * LINE, v[j]);
    (void)__hip_atomic_fetch_add(cnt, 1u, __ATOMIC_RELEASE, __HIP_MEMORY_SCOPE_AGENT);
}

template<int NV>
__device__ inline void evt_consume(float* vbase, uint_t* cnt, uint_t tgt, float* red) {
    while (__hip_atomic_load(cnt, __ATOMIC_RELAXED, __HIP_MEMORY_SCOPE_AGENT) < tgt)
        __builtin_amdgcn_s_sleep(2);
    (void)__hip_atomic_load(cnt, __ATOMIC_ACQUIRE, __HIP_MEMORY_SCOPE_AGENT);
    #pragma unroll
    for (int j = 0; j < NV; ++j) {
        float s = 0.f;
        #pragma unroll
        for (int q = 0; q < 4; ++q) s += aload(vbase + (j * 4 + q) * LINE);
        red[j] = s;
    }
}

// ---------- prep: frag-linear bf16 layouts + zero sync region ----------
__global__ __launch_bounds__(256) void k_pre(
    const float* __restrict__ Ar, const float* __restrict__ Ai,
    const float* __restrict__ Dr, const float* __restrict__ Di,
    ushort_t* __restrict__ Afr, ushort_t* __restrict__ Afi,
    ushort_t* __restrict__ Atr, ushort_t* __restrict__ Ati,
    ushort_t* __restrict__ Dfr, ushort_t* __restrict__ Dfi,
    uint_t* __restrict__ syncbuf)
{
    const int gt = blockIdx.x * 256 + threadIdx.x;
    const int gs = gridDim.x * 256;
    for (int idx = gt; idx < SYNC_DW; idx += gs) syncbuf[idx] = 0u;
    for (int idx = gt; idx < L_ * 32768; idx += gs) {
        int j = idx & 7, rest = idx >> 3;
        int mm = rest & 15; rest >>= 4;
        int qq = rest & 3;  rest >>= 2;
        int k2 = rest & 1;  rest >>= 1;
        int tile = rest & 31;
        int l = rest >> 5;
        int t = tile * 16 + mm, k = k2 * 32 + qq * 8 + j;
        float vr = 0.f, vi = 0.f;
        if (k < 48) { int g = l * 24576 + t * 48 + k; vr = Ar[g]; vi = Ai[g]; }
        Afr[idx] = f2bf(vr); Afi[idx] = f2bf(vi);
    }
    for (int idx = gt; idx < L_ * 24576; idx += gs) {
        int j = idx & 7, rest = idx >> 3;
        int mm = rest & 15; rest >>= 4;
        int qq = rest & 3;  rest >>= 2;
        int ks = rest & 15; rest >>= 4;
        int ft = rest % 3;
        int l = rest / 3;
        int f = ft * 16 + mm, k = ks * 32 + qq * 8 + j;
        int g = l * 24576 + k * 48 + f;
        Atr[idx] = f2bf(Ar[g]); Ati[idx] = f2bf(Ai[g]);
    }
    for (int idx = gt; idx < 24576; idx += gs) {
        int j = idx & 7, rest = idx >> 3;
        int mm = rest & 15; rest >>= 4;
        int qq = rest & 3;  rest >>= 2;
        int ks = rest & 15;
        int ft = rest >> 4;
        int f = ft * 16 + mm, k = ks * 32 + qq * 8 + j;
        Dfr[idx] = f2bf(Dr[k * 48 + f]); Dfi[idx] = f2bf(Di[k * 48 + f]);
    }
}

// ---------- persistent cooperative kernel ----------
// 8 global sync events total (R1 transport, R3 algebra):
//   event 0:   sigma_0 partials (||u||^2)
//   event l+1: layer l (l=0..6) payload {cnt_re, cnt_im, S1..S6} where
//              a = u - h and ||z_new||^2 = S(a^2) + 2b S(a z) + b^2 S(z^2)
//              per re/im component; every block derives b_l AND sigma_{l+1}.
__global__ __launch_bounds__(THR, 2) void k_lamp(
    const float* __restrict__ u,
    const ushort_t* __restrict__ Afr, const ushort_t* __restrict__ Afi,
    const ushort_t* __restrict__ Atr, const ushort_t* __restrict__ Ati,
    const ushort_t* __restrict__ Dfr, const ushort_t* __restrict__ Dfi,
    const float* __restrict__ th,
    uint_t* syncbuf,
    float* __restrict__ out)
{
    extern __shared__ char dyn[];
    float*    pR   = (float*)dyn;                  // [8][3][16][17] 26112 B
    float*    pI   = pR + 8 * 3 * 16 * 17;         // 26112 B
    float*    zreL = pI + 8 * 3 * 16 * 17;         // 6656 B
    float*    zimL = zreL + RPB * ZS;              // 6656 B
    float*    red  = zimL + RPB * ZS;              // 512 B (128 floats)
    ushort_t* HreL = (ushort_t*)(red + 128);       // 33280 B
    ushort_t* HimL = HreL + RPB * HST;             // 33280 B  => 132608 B

    uint_t* cnt = syncbuf;                                   // counter line
    float*  ev0 = (float*)syncbuf + (size_t)1 * LINE;        // event bases
    auto evb = [&](int e) { return ev0 + (size_t)e * EVT_LINES * LINE; };

    const int tid = threadIdx.x, blk = blockIdx.x;
    const int row0 = blk * RPB;
    const int wave = tid >> 6, lane = tid & 63;
    const int quad = lane >> 4, m = lane & 15;
    const int rows16 = (wave >> 2) * 16;           // fwd: which 16-row tile
    const int rt = wave >> 2, kq = wave & 3;       // bwd: row-tile / K-quarter
    const float2* u2 = (const float2*)u;

    // persistent H fragments (f32): H[ct][reg] at (row=rows16+quad*4+reg, col=tile*16+m)
    f32x4 hR[8], hI[8];
    #pragma unroll
    for (int ct = 0; ct < 8; ++ct) { hR[ct] = (f32x4){0,0,0,0}; hI[ct] = (f32x4){0,0,0,0}; }

    // prologue: u -> z LDS, ||u||^2 partial -> event 0
    float acc = 0.f;
    #pragma unroll
    for (int k3 = 0; k3 < 3; ++k3) {
        int j = tid + k3 * THR;
        int r = j / 48, c = j - r * 48;
        float2 v = u2[(row0 + r) * 48 + c];
        zreL[r * ZS + c] = v.x; zimL[r * ZS + c] = v.y;
        acc += v.x * v.x + v.y * v.y;
    }
    #pragma unroll
    for (int o = 32; o > 0; o >>= 1) acc += __shfl_xor(acc, o, 64);
    __syncthreads();                         // publishes z LDS
    if (lane == 0) red[16 + wave] = acc;
    __syncthreads();
    if (tid == 0) {
        float t = 0.f;
        #pragma unroll
        for (int w = 0; w < NW; ++w) t += red[16 + w];
        evt_publish<1>(evb(0), cnt, blk, &t);
    }

    float lam = 0.f;
    for (int l = 0; l < L_; ++l) {
        const float th1 = th[l * 3 + 1];

        // z A-frags from LDS fp32 (K=48 padded to 64)
        const float* zpr = zreL + (rows16 + m) * ZS;
        const float* zpi = zimL + (rows16 + m) * ZS;
        short8 zr0 = pack8(*(const float4*)(zpr + quad * 8), *(const float4*)(zpr + quad * 8 + 4));
        short8 zi0 = pack8(*(const float4*)(zpi + quad * 8), *(const float4*)(zpi + quad * 8 + 4));
        short8 zr1 = {0,0,0,0,0,0,0,0}, zi1 = {0,0,0,0,0,0,0,0};
        if (quad < 2) {
            zr1 = pack8(*(const float4*)(zpr + 32 + quad * 8), *(const float4*)(zpr + 36 + quad * 8));
            zi1 = pack8(*(const float4*)(zpi + 32 + quad * 8), *(const float4*)(zpi + 36 + quad * 8));
        }
        short8 zin0 = negbf(zi0), zin1 = negbf(zi1);

        // forward GEMM accumulating straight onto H_old (R = H + Z in registers)
        const ushort_t* Aflr = Afr + (size_t)l * 32768;
        const ushort_t* Afli = Afi + (size_t)l * 32768;
        #pragma unroll
        for (int ct = 0; ct < 8; ++ct) {
            const int tile = (wave & 3) * 8 + ct;
            const ushort_t* rp = Aflr + (size_t)(tile * 2) * 512 + lane * 8;
            const ushort_t* ip = Afli + (size_t)(tile * 2) * 512 + lane * 8;
            short8 ar0 = *(const short8*)rp;
            short8 ar1 = *(const short8*)(rp + 512);
            short8 ai0 = *(const short8*)ip;
            short8 ai1 = *(const short8*)(ip + 512);
            hR[ct] = MFMA(zr0, ar0, hR[ct]);
            hR[ct] = MFMA(zr1, ar1, hR[ct]);
            hR[ct] = MFMA(zin0, ai0, hR[ct]);
            hR[ct] = MFMA(zin1, ai1, hR[ct]);
            hI[ct] = MFMA(zr0, ai0, hI[ct]);
            hI[ct] = MFMA(zr1, ai1, hI[ct]);
            hI[ct] = MFMA(zi0, ar0, hI[ct]);
            hI[ct] = MFMA(zi1, ar1, hI[ct]);
        }

        // sigma_0 wait hides behind the first fwd GEMM; later layers already
        // derived lam locally from the previous layer's event.
        if (l == 0) {
            if (tid == 0) evt_consume<1>(evb(0), cnt, (uint_t)NBLK, red);
            __syncthreads();
            lam = th[0] * sqrtf(red[0] * (1.0f / 48.0f));
        }

        // activation on registers: Hn = act(R); store Hn bf16 to LDS for bwd GEMM
        float cr = 0.f, ci = 0.f;
        #pragma unroll
        for (int ct = 0; ct < 8; ++ct) {
            const int t = ((wave & 3) * 8 + ct) * 16 + m;
            #pragma unroll
            for (int reg = 0; reg < 4; ++reg) {
                const int lr = rows16 + quad * 4 + reg;
                float Rr = hR[ct][reg], Ri = hI[ct][reg];
                float mr = fabsf(Rr), mi = fabsf(Ri);
                float fr = th1 * copysignf(fmaxf(mr - lam, 0.f), Rr);
                float fi = th1 * copysignf(fmaxf(mi - lam, 0.f), Ri);
                cr += (mr > lam) ? 1.f : 0.f;
                ci += (mi > lam) ? 1.f : 0.f;
                hR[ct][reg] = fr; hI[ct][reg] = fi;
                HreL[lr * HST + t] = f2bf(fr);
                HimL[lr * HST + t] = f2bf(fi);
            }
        }

        if (l == L_ - 1) { __syncthreads(); break; }   // publish Hn for final GEMM
        __syncthreads();                               // publish Hn for bwd GEMM

        // backward GEMM: h = Hn @ A; wave (rt,kq) does rows rt*16..+16, K quarter kq
        const ushort_t* Atlr = Atr + (size_t)l * 24576;
        const ushort_t* Atli = Ati + (size_t)l * 24576;
        f32x4 aR[3], aI[3];
        #pragma unroll
        for (int q = 0; q < 3; ++q) { aR[q] = (f32x4){0,0,0,0}; aI[q] = (f32x4){0,0,0,0}; }
        #pragma unroll
        for (int ks = 0; ks < 4; ++ks) {
            const int ksa = kq * 4 + ks;
            const int k0 = ksa * 32 + quad * 8;
            short8 hr = *(const short8*)&HreL[(rt * 16 + m) * HST + k0];
            short8 hi = *(const short8*)&HimL[(rt * 16 + m) * HST + k0];
            short8 hin = negbf(hi);
            #pragma unroll
            for (int ft = 0; ft < 3; ++ft) {
                short8 br = *(const short8*)(Atlr + (size_t)((ft * 16 + ksa) * 64 + lane) * 8);
                short8 bi = *(const short8*)(Atli + (size_t)((ft * 16 + ksa) * 64 + lane) * 8);
                aR[ft] = MFMA(hr, br, aR[ft]);
                aR[ft] = MFMA(hin, bi, aR[ft]);
                aI[ft] = MFMA(hr, bi, aI[ft]);
                aI[ft] = MFMA(hi, br, aI[ft]);
            }
        }
        #pragma unroll
        for (int ft = 0; ft < 3; ++ft) {
            #pragma unroll
            for (int reg = 0; reg < 4; ++reg) {
                pR[((wave * 3 + ft) * 16 + quad * 4 + reg) * 17 + m] = aR[ft][reg];
                pI[((wave * 3 + ft) * 16 + quad * 4 + reg) * 17 + m] = aI[ft][reg];
            }
        }
        __syncthreads();                               // publish pR/pI

        // quadratic partials: a = u - h, vs z_old (kept in registers for z write)
        float aRe[3], aIm[3], zR3[3], zI3[3];
        float S1 = 0.f, S2 = 0.f, S3 = 0.f, S4 = 0.f, S5 = 0.f, S6 = 0.f;
        #pragma unroll
        for (int k3 = 0; k3 < 3; ++k3) {
            int j = tid + k3 * THR;
            int r = j / 48, f = j - r * 48;
            int rt2 = r >> 4, lr = r & 15, ft = f >> 4, c = f & 15;
            float hRv = 0.f, hIv = 0.f;
            #pragma unroll
            for (int q = 0; q < 4; ++q) {
                hRv += pR[(((rt2 * 4 + q) * 3 + ft) * 16 + lr) * 17 + c];
                hIv += pI[(((rt2 * 4 + q) * 3 + ft) * 16 + lr) * 17 + c];
            }
            float2 uv = u2[(row0 + r) * 48 + f];
            float zr = zreL[r * ZS + f], zi = zimL[r * ZS + f];
            float ar = uv.x - hRv, ai = uv.y - hIv;
            aRe[k3] = ar; aIm[k3] = ai; zR3[k3] = zr; zI3[k3] = zi;
            S1 += ar * ar; S2 += ar * zr; S3 += zr * zr;
            S4 += ai * ai; S5 += ai * zi; S6 += zi * zi;
        }

        // block-reduce 8 values, publish + consume event l+1 (tid 0 only)
        float v8[8] = {cr, ci, S1, S2, S3, S4, S5, S6};
        #pragma unroll
        for (int j = 0; j < 8; ++j) {
            #pragma unroll
            for (int o = 32; o > 0; o >>= 1) v8[j] += __shfl_xor(v8[j], o, 64);
        }
        if (lane == 0) {
            #pragma unroll
            for (int j = 0; j < 8; ++j) red[16 + wave * 8 + j] = v8[j];
        }
        __syncthreads();
        if (tid == 0) {
            float o8[8];
            #pragma unroll
            for (int j = 0; j < 8; ++j) {
                float s = 0.f;
                #pragma unroll
                for (int w = 0; w < NW; ++w) s += red[16 + w * 8 + j];
                o8[j] = s;
            }
            float* vb = evb(l + 1);
            evt_publish<8>(vb, cnt, blk, o8);
            evt_consume<8>(vb, cnt, (uint_t)NBLK * (uint_t)(l + 2), red);
        }
        __syncthreads();

        const float CR = red[0], CI = red[1];
        const float G1 = red[2], G2 = red[3], G3 = red[4];
        const float G4 = red[5], G5 = red[6], G6 = red[7];
        const float bre = th1 * CR * (1.0f / 48.0f);
        const float bim = th1 * CI * (1.0f / 48.0f);
        const float sig2 = G1 + 2.f * bre * G2 + bre * bre * G3
                         + G4 + 2.f * bim * G5 + bim * bim * G6;
        lam = th[(l + 1) * 3] * sqrtf(sig2 * (1.0f / 48.0f));

        // z write from cached registers
        #pragma unroll
        for (int k3 = 0; k3 < 3; ++k3) {
            int j = tid + k3 * THR;
            int r = j / 48, f = j - r * 48;
            zreL[r * ZS + f] = aRe[k3] + bre * zR3[k3];
            zimL[r * ZS + f] = aIm[k3] + bim * zI3[k3];
        }
        __syncthreads();                 // z published for next fwd GEMM
    }

    // final: out = Hn(LDS) @ DFT  (wave (rt,kq), K-split, LDS combine)
    f32x4 fR[3], fI[3];
    #pragma unroll
    for (int q = 0; q < 3; ++q) { fR[q] = (f32x4){0,0,0,0}; fI[q] = (f32x4){0,0,0,0}; }
    #pragma unroll
    for (int ks = 0; ks < 4; ++ks) {
        const int ksa = kq * 4 + ks;
        const int k0 = ksa * 32 + quad * 8;
        short8 hr = *(const short8*)&HreL[(rt * 16 + m) * HST + k0];
        short8 hi = *(const short8*)&HimL[(rt * 16 + m) * HST + k0];
        short8 hin = negbf(hi);
        #pragma unroll
        for (int ft = 0; ft < 3; ++ft) {
            short8 br = *(const short8*)(Dfr + (size_t)((ft * 16 + ksa) * 64 + lane) * 8);
            short8 bi = *(const short8*)(Dfi + (size_t)((ft * 16 + ksa) * 64 + lane) * 8);
            fR[ft] = MFMA(hr, br, fR[ft]);
            fR[ft] = MFMA(hin, bi, fR[ft]);
            fI[ft] = MFMA(hr, bi, fI[ft]);
            fI[ft] = MFMA(hi, br, fI[ft]);
        }
    }
    #pragma unroll
    for (int ft = 0; ft < 3; ++ft) {
        #pragma unroll
        for (int reg = 0; reg < 4; ++reg) {
            pR[((wave * 3 + ft) * 16 + quad * 4 + reg) * 17 + m] = fR[ft][reg];
            pI[((wave * 3 + ft) * 16 + quad * 4 + reg) * 17 + m] = fI[ft][reg];
        }
    }
    __syncthreads();
    float2* out2 = (float2*)out;
    #pragma unroll
    for (int k3 = 0; k3 < 3; ++k3) {
        int j = tid + k3 * THR;
        int r = j / 48, f = j - r * 48;
        int rt2 = r >> 4, lr = r & 15, ft = f >> 4, c = f & 15;
        float hRv = 0.f, hIv = 0.f;
        #pragma unroll
        for (int q = 0; q < 4; ++q) {
            hRv += pR[(((rt2 * 4 + q) * 3 + ft) * 16 + lr) * 17 + c];
            hIv += pI[(((rt2 * 4 + q) * 3 + ft) * 16 + lr) * 17 + c];
        }
        out2[(row0 + r) * 48 + f] = make_float2(hRv, hIv);
    }
}

extern "C" void kernel_launch(void* const* d_in, const int* in_sizes, int n_in,
                              void* d_out, int out_size, void* d_ws, size_t ws_size,
                              hipStream_t stream) {
    (void)in_sizes; (void)n_in; (void)out_size; (void)ws_size;
    const float* u  = (const float*)d_in[0];
    const float* Ar = (const float*)d_in[1];
    const float* Ai = (const float*)d_in[2];
    const float* th = (const float*)d_in[3];
    const float* Dr = (const float*)d_in[4];
    const float* Di = (const float*)d_in[5];
    float* out = (float*)d_out;

    char* p = (char*)d_ws;
    auto alloc = [&](size_t bytes) -> char* {
        char* r = p;
        p += (bytes + 255) & ~(size_t)255;
        return r;
    };
    uint_t*   syncbuf = (uint_t*)alloc((size_t)SYNC_DW * 4);
    ushort_t* Afr = (ushort_t*)alloc((size_t)L_ * 32768 * 2);
    ushort_t* Afi = (ushort_t*)alloc((size_t)L_ * 32768 * 2);
    ushort_t* Atr = (ushort_t*)alloc((size_t)L_ * 24576 * 2);
    ushort_t* Ati = (ushort_t*)alloc((size_t)L_ * 24576 * 2);
    ushort_t* Dfr = (ushort_t*)alloc((size_t)24576 * 2);
    ushort_t* Dfi = (ushort_t*)alloc((size_t)24576 * 2);

    k_pre<<<1024, 256, 0, stream>>>(Ar, Ai, Dr, Di, Afr, Afi, Atr, Ati, Dfr, Dfi, syncbuf);

    const uint_t lds_bytes = 132608;
    hipFuncSetAttribute((const void*)k_lamp,
                        hipFuncAttributeMaxDynamicSharedMemorySize, (int)lds_bytes);
    void* args[] = { (void*)&u, (void*)&Afr, (void*)&Afi, (void*)&Atr, (void*)&Ati,
                     (void*)&Dfr, (void*)&Dfi, (void*)&th,
                     (void*)&syncbuf, (void*)&out };
    hipLaunchCooperativeKernel((void*)k_lamp, dim3(NBLK), dim3(THR), args,
                               lds_bytes, stream);
}

// Round 6
// 270.467 us; speedup vs baseline: 1.1377x; 1.0586x over previous
//
#include <hip/hip_runtime.h>
#include <hip/hip_bf16.h>
#include <math.h>

#define B_   8192
#define F_   48
#define T_   512
#define L_   8
#define NBLK 256
#define THR  512
#define NW   8           // waves per block
#define RPB  32          // rows per block
#define HST  520         // H LDS row stride in shorts (1040B; 65 uint4)
#define ZS   52          // z LDS row stride in floats
#define LINE 32          // dwords per 128B line
#define NEVT 15          // E0 + (A_l,B_l) x 7 layers
#define SLOT_DW (NBLK * LINE)                     // per-event slot region
#define SYNC_DW ((1 + NEVT * NBLK) * LINE)        // counter line + slots

typedef unsigned short ushort_t;
typedef unsigned int   uint_t;
typedef __attribute__((ext_vector_type(8))) short short8;
typedef __attribute__((ext_vector_type(4))) float f32x4;

#define MFMA(a,b,c) __builtin_amdgcn_mfma_f32_16x16x32_bf16(a,b,c,0,0,0)

__device__ inline ushort_t f2bf(float x) {
    __hip_bfloat16 h = __float2bfloat16(x);
    return *reinterpret_cast<ushort_t*>(&h);
}
__device__ inline short8 negbf(short8 v) {
    short8 r;
    #pragma unroll
    for (int i = 0; i < 8; ++i) r[i] = v[i] ^ (short)0x8000;
    return r;
}
__device__ inline short8 pack8(float4 a, float4 b) {
    short8 r;
    r[0]=(short)f2bf(a.x); r[1]=(short)f2bf(a.y); r[2]=(short)f2bf(a.z); r[3]=(short)f2bf(a.w);
    r[4]=(short)f2bf(b.x); r[5]=(short)f2bf(b.y); r[6]=(short)f2bf(b.z); r[7]=(short)f2bf(b.w);
    return r;
}

__device__ inline float aload(const float* p) {
    return __hip_atomic_load(p, __ATOMIC_RELAXED, __HIP_MEMORY_SCOPE_AGENT);
}
__device__ inline void astore(float* p, float v) {
    __hip_atomic_store(p, v, __ATOMIC_RELAXED, __HIP_MEMORY_SCOPE_AGENT);
}

// ---------- prep: frag-linear bf16 layouts + zero counter line ----------
__global__ __launch_bounds__(256) void k_pre(
    const float* __restrict__ Ar, const float* __restrict__ Ai,
    const float* __restrict__ Dr, const float* __restrict__ Di,
    ushort_t* __restrict__ Afr, ushort_t* __restrict__ Afi,
    ushort_t* __restrict__ Atr, ushort_t* __restrict__ Ati,
    ushort_t* __restrict__ Dfr, ushort_t* __restrict__ Dfi,
    uint_t* __restrict__ syncbuf)
{
    const int gt = blockIdx.x * 256 + threadIdx.x;
    const int gs = gridDim.x * 256;
    if (gt < LINE) syncbuf[gt] = 0u;   // slots need no zeroing (stores, not adds)
    for (int idx = gt; idx < L_ * 32768; idx += gs) {
        int j = idx & 7, rest = idx >> 3;
        int mm = rest & 15; rest >>= 4;
        int qq = rest & 3;  rest >>= 2;
        int k2 = rest & 1;  rest >>= 1;
        int tile = rest & 31;
        int l = rest >> 5;
        int t = tile * 16 + mm, k = k2 * 32 + qq * 8 + j;
        float vr = 0.f, vi = 0.f;
        if (k < 48) { int g = l * 24576 + t * 48 + k; vr = Ar[g]; vi = Ai[g]; }
        Afr[idx] = f2bf(vr); Afi[idx] = f2bf(vi);
    }
    for (int idx = gt; idx < L_ * 24576; idx += gs) {
        int j = idx & 7, rest = idx >> 3;
        int mm = rest & 15; rest >>= 4;
        int qq = rest & 3;  rest >>= 2;
        int ks = rest & 15; rest >>= 4;
        int ft = rest % 3;
        int l = rest / 3;
        int f = ft * 16 + mm, k = ks * 32 + qq * 8 + j;
        int g = l * 24576 + k * 48 + f;
        Atr[idx] = f2bf(Ar[g]); Ati[idx] = f2bf(Ai[g]);
    }
    for (int idx = gt; idx < 24576; idx += gs) {
        int j = idx & 7, rest = idx >> 3;
        int mm = rest & 15; rest >>= 4;
        int qq = rest & 3;  rest >>= 2;
        int ks = rest & 15;
        int ft = rest >> 4;
        int f = ft * 16 + mm, k = ks * 32 + qq * 8 + j;
        Dfr[idx] = f2bf(Dr[k * 48 + f]); Dfi[idx] = f2bf(Di[k * 48 + f]);
    }
}

// ---------- persistent kernel (regular launch; 256 blocks = 1/CU by LDS) ----
// Events (global order, cumulative counter target = 256*(e+1)):
//   e=0:      sigma_0 (1 val)  publish prologue, consume after fwd GEMM 0
//   e=2l+1:   A_l {cr,ci}      publish after act_l, consume after bwd GEMM l
//   e=2l+2:   B_l {S1..S6}     publish before z-write, consume after fwd GEMM l+1
// sigma_{l+1}^2 = S1+2*bre*S2+bre^2*S3 + S4+2*bim*S5+bim^2*S6 (quadratic algebra).
__global__ __launch_bounds__(THR, 2) void k_lamp(
    const float* __restrict__ u,
    const ushort_t* __restrict__ Afr, const ushort_t* __restrict__ Afi,
    const ushort_t* __restrict__ Atr, const ushort_t* __restrict__ Ati,
    const ushort_t* __restrict__ Dfr, const ushort_t* __restrict__ Dfi,
    const float* __restrict__ th,
    uint_t* syncbuf,
    float* __restrict__ out)
{
    extern __shared__ char dyn[];
    float*    pR   = (float*)dyn;                  // [8][3][16][17] 26112 B
    float*    pI   = pR + 8 * 3 * 16 * 17;         // 26112 B
    float*    zreL = pI + 8 * 3 * 16 * 17;         // 6656 B
    float*    zimL = zreL + RPB * ZS;              // 6656 B
    float*    red  = zimL + RPB * ZS;              // 512 B (128 floats)
    ushort_t* HreL = (ushort_t*)(red + 128);       // 33280 B
    ushort_t* HimL = HreL + RPB * HST;             // 33280 B  => 132608 B

    uint_t* cnt   = syncbuf;                       // counter line
    float*  slots = (float*)syncbuf + LINE;        // event e: slots + e*SLOT_DW

    const int tid = threadIdx.x, blk = blockIdx.x;
    const int row0 = blk * RPB;
    const int wave = tid >> 6, lane = tid & 63;
    const int quad = lane >> 4, m = lane & 15;
    const int rows16 = (wave >> 2) * 16;           // fwd: which 16-row tile
    const int rt = wave >> 2, kq = wave & 3;       // bwd: row-tile / K-quarter
    const float2* u2 = (const float2*)u;

    // tid0: write this block's slot line (plain relaxed atomic stores, no RMW)
    // then release-bump the cumulative counter.
    auto publishv = [&](int e, const float* v, int nv) {
        float* line = slots + (size_t)e * SLOT_DW + (size_t)blk * LINE;
        for (int j = 0; j < nv; ++j) astore(line + j, v[j]);
        (void)__hip_atomic_fetch_add(cnt, 1u, __ATOMIC_RELEASE,
                                     __HIP_MEMORY_SCOPE_AGENT);
    };
    // tid0 polls counter; waves 0..nv-1 gather value w across 256 slot lines
    // in parallel (4 loads/lane) and shuffle-reduce into red[w].
    auto consume = [&](int e, int nv) {
        if (tid == 0) {
            uint_t tgt = (uint_t)NBLK * (uint_t)(e + 1);
            int spin = 0;
            while (__hip_atomic_load(cnt, __ATOMIC_RELAXED,
                                     __HIP_MEMORY_SCOPE_AGENT) < tgt) {
                if (++spin > 2) __builtin_amdgcn_s_sleep(8);
            }
            (void)__hip_atomic_load(cnt, __ATOMIC_ACQUIRE,
                                    __HIP_MEMORY_SCOPE_AGENT);
        }
        __syncthreads();
        if (wave < nv) {
            const float* base = slots + (size_t)e * SLOT_DW;
            float s = 0.f;
            #pragma unroll
            for (int g = 0; g < 4; ++g)
                s += aload(base + (size_t)(g * 64 + lane) * LINE + wave);
            #pragma unroll
            for (int o = 32; o > 0; o >>= 1) s += __shfl_xor(s, o, 64);
            if (lane == 0) red[wave] = s;
        }
        __syncthreads();
    };

    // persistent H fragments (f32)
    f32x4 hR[8], hI[8];
    #pragma unroll
    for (int ct = 0; ct < 8; ++ct) { hR[ct] = (f32x4){0,0,0,0}; hI[ct] = (f32x4){0,0,0,0}; }

    // prologue: u -> regs + z LDS; ||u||^2 partial -> event 0
    float uRe[3], uIm[3];
    float acc = 0.f;
    #pragma unroll
    for (int k3 = 0; k3 < 3; ++k3) {
        int j = tid + k3 * THR;
        int r = j / 48, c = j - r * 48;
        float2 v = u2[(row0 + r) * 48 + c];
        uRe[k3] = v.x; uIm[k3] = v.y;
        zreL[r * ZS + c] = v.x; zimL[r * ZS + c] = v.y;
        acc += v.x * v.x + v.y * v.y;
    }
    #pragma unroll
    for (int o = 32; o > 0; o >>= 1) acc += __shfl_xor(acc, o, 64);
    __syncthreads();                         // publishes z LDS
    if (lane == 0) red[16 + wave] = acc;
    __syncthreads();
    if (tid == 0) {
        float t = 0.f;
        #pragma unroll
        for (int w = 0; w < NW; ++w) t += red[16 + w];
        publishv(0, &t, 1);
    }

    float lam = 0.f, bre = 0.f, bim = 0.f;
    for (int l = 0; l < L_; ++l) {
        const float th1 = th[l * 3 + 1];

        // z A-frags from LDS fp32 (K=48 padded to 64)
        const float* zpr = zreL + (rows16 + m) * ZS;
        const float* zpi = zimL + (rows16 + m) * ZS;
        short8 zr0 = pack8(*(const float4*)(zpr + quad * 8), *(const float4*)(zpr + quad * 8 + 4));
        short8 zi0 = pack8(*(const float4*)(zpi + quad * 8), *(const float4*)(zpi + quad * 8 + 4));
        short8 zr1 = {0,0,0,0,0,0,0,0}, zi1 = {0,0,0,0,0,0,0,0};
        if (quad < 2) {
            zr1 = pack8(*(const float4*)(zpr + 32 + quad * 8), *(const float4*)(zpr + 36 + quad * 8));
            zi1 = pack8(*(const float4*)(zpi + 32 + quad * 8), *(const float4*)(zpi + 36 + quad * 8));
        }
        short8 zin0 = negbf(zi0), zin1 = negbf(zi1);

        // forward GEMM accumulating straight onto H_old
        const ushort_t* Aflr = Afr + (size_t)l * 32768;
        const ushort_t* Afli = Afi + (size_t)l * 32768;
        #pragma unroll
        for (int ct = 0; ct < 8; ++ct) {
            const int tile = (wave & 3) * 8 + ct;
            const ushort_t* rp = Aflr + (size_t)(tile * 2) * 512 + lane * 8;
            const ushort_t* ip = Afli + (size_t)(tile * 2) * 512 + lane * 8;
            short8 ar0 = *(const short8*)rp;
            short8 ar1 = *(const short8*)(rp + 512);
            short8 ai0 = *(const short8*)ip;
            short8 ai1 = *(const short8*)(ip + 512);
            hR[ct] = MFMA(zr0, ar0, hR[ct]);
            hR[ct] = MFMA(zr1, ar1, hR[ct]);
            hR[ct] = MFMA(zin0, ai0, hR[ct]);
            hR[ct] = MFMA(zin1, ai1, hR[ct]);
            hI[ct] = MFMA(zr0, ai0, hI[ct]);
            hI[ct] = MFMA(zr1, ai1, hI[ct]);
            hI[ct] = MFMA(zi0, ar0, hI[ct]);
            hI[ct] = MFMA(zi1, ar1, hI[ct]);
        }

        // lambda event consume (hidden behind the fwd GEMM above)
        if (l == 0) {
            consume(0, 1);
            lam = th[0] * sqrtf(red[0] * (1.0f / 48.0f));
        } else {
            consume(2 * l, 6);                    // B_{l-1}
            float sig2 = red[0] + 2.f * bre * red[1] + bre * bre * red[2]
                       + red[3] + 2.f * bim * red[4] + bim * bim * red[5];
            lam = th[l * 3] * sqrtf(sig2 * (1.0f / 48.0f));
        }

        // activation on registers; store Hn bf16 to LDS for bwd/final GEMM
        float cr = 0.f, ci = 0.f;
        #pragma unroll
        for (int ct = 0; ct < 8; ++ct) {
            const int t = ((wave & 3) * 8 + ct) * 16 + m;
            #pragma unroll
            for (int reg = 0; reg < 4; ++reg) {
                const int lr = rows16 + quad * 4 + reg;
                float Rr = hR[ct][reg], Ri = hI[ct][reg];
                float mr = fabsf(Rr), mi = fabsf(Ri);
                float fr = th1 * copysignf(fmaxf(mr - lam, 0.f), Rr);
                float fi = th1 * copysignf(fmaxf(mi - lam, 0.f), Ri);
                cr += (mr > lam) ? 1.f : 0.f;
                ci += (mi > lam) ? 1.f : 0.f;
                hR[ct][reg] = fr; hI[ct][reg] = fi;
                HreL[lr * HST + t] = f2bf(fr);
                HimL[lr * HST + t] = f2bf(fi);
            }
        }

        if (l == L_ - 1) { __syncthreads(); break; }   // publish Hn for final GEMM

        // reduce {cr,ci}; publish A_l right before bwd GEMM (wait hides behind it)
        #pragma unroll
        for (int o = 32; o > 0; o >>= 1) { cr += __shfl_xor(cr, o, 64); ci += __shfl_xor(ci, o, 64); }
        if (lane == 0) { red[16 + wave] = cr; red[24 + wave] = ci; }
        __syncthreads();                               // also publishes Hn LDS
        if (tid == 0) {
            float v2[2] = {0.f, 0.f};
            #pragma unroll
            for (int w = 0; w < NW; ++w) { v2[0] += red[16 + w]; v2[1] += red[24 + w]; }
            publishv(2 * l + 1, v2, 2);
        }

        // backward GEMM: h = Hn @ A
        const ushort_t* Atlr = Atr + (size_t)l * 24576;
        const ushort_t* Atli = Ati + (size_t)l * 24576;
        f32x4 aR[3], aI[3];
        #pragma unroll
        for (int q = 0; q < 3; ++q) { aR[q] = (f32x4){0,0,0,0}; aI[q] = (f32x4){0,0,0,0}; }
        #pragma unroll
        for (int ks = 0; ks < 4; ++ks) {
            const int ksa = kq * 4 + ks;
            const int k0 = ksa * 32 + quad * 8;
            short8 hr = *(const short8*)&HreL[(rt * 16 + m) * HST + k0];
            short8 hi = *(const short8*)&HimL[(rt * 16 + m) * HST + k0];
            short8 hin = negbf(hi);
            #pragma unroll
            for (int ft = 0; ft < 3; ++ft) {
                short8 br = *(const short8*)(Atlr + (size_t)((ft * 16 + ksa) * 64 + lane) * 8);
                short8 bi = *(const short8*)(Atli + (size_t)((ft * 16 + ksa) * 64 + lane) * 8);
                aR[ft] = MFMA(hr, br, aR[ft]);
                aR[ft] = MFMA(hin, bi, aR[ft]);
                aI[ft] = MFMA(hr, bi, aI[ft]);
                aI[ft] = MFMA(hi, br, aI[ft]);
            }
        }
        #pragma unroll
        for (int ft = 0; ft < 3; ++ft) {
            #pragma unroll
            for (int reg = 0; reg < 4; ++reg) {
                pR[((wave * 3 + ft) * 16 + quad * 4 + reg) * 17 + m] = aR[ft][reg];
                pI[((wave * 3 + ft) * 16 + quad * 4 + reg) * 17 + m] = aI[ft][reg];
            }
        }
        __syncthreads();                               // publish pR/pI

        // consume A_l (hidden behind bwd GEMM) -> b
        consume(2 * l + 1, 2);
        bre = th1 * red[0] * (1.0f / 48.0f);
        bim = th1 * red[1] * (1.0f / 48.0f);

        // quadratic partials (a = u - h from REGISTERS; z_old from LDS)
        float aRe[3], aIm[3], zR3[3], zI3[3];
        float S1 = 0.f, S2 = 0.f, S3 = 0.f, S4 = 0.f, S5 = 0.f, S6 = 0.f;
        #pragma unroll
        for (int k3 = 0; k3 < 3; ++k3) {
            int j = tid + k3 * THR;
            int r = j / 48, f = j - r * 48;
            int rt2 = r >> 4, lr = r & 15, ft = f >> 4, c = f & 15;
            float hRv = 0.f, hIv = 0.f;
            #pragma unroll
            for (int q = 0; q < 4; ++q) {
                hRv += pR[(((rt2 * 4 + q) * 3 + ft) * 16 + lr) * 17 + c];
                hIv += pI[(((rt2 * 4 + q) * 3 + ft) * 16 + lr) * 17 + c];
            }
            float zr = zreL[r * ZS + f], zi = zimL[r * ZS + f];
            float ar = uRe[k3] - hRv, ai = uIm[k3] - hIv;
            aRe[k3] = ar; aIm[k3] = ai; zR3[k3] = zr; zI3[k3] = zi;
            S1 += ar * ar; S2 += ar * zr; S3 += zr * zr;
            S4 += ai * ai; S5 += ai * zi; S6 += zi * zi;
        }

        // reduce S1..S6; publish B_l before the z-write (consumed after next fwd)
        float v6[6] = {S1, S2, S3, S4, S5, S6};
        #pragma unroll
        for (int j = 0; j < 6; ++j) {
            #pragma unroll
            for (int o = 32; o > 0; o >>= 1) v6[j] += __shfl_xor(v6[j], o, 64);
        }
        if (lane == 0) {
            #pragma unroll
            for (int j = 0; j < 6; ++j) red[16 + wave * 6 + j] = v6[j];
        }
        __syncthreads();
        if (tid == 0) {
            float o6[6];
            #pragma unroll
            for (int j = 0; j < 6; ++j) {
                float s = 0.f;
                #pragma unroll
                for (int w = 0; w < NW; ++w) s += red[16 + w * 6 + j];
                o6[j] = s;
            }
            publishv(2 * l + 2, o6, 6);
        }

        // z write from cached registers
        #pragma unroll
        for (int k3 = 0; k3 < 3; ++k3) {
            int j = tid + k3 * THR;
            int r = j / 48, f = j - r * 48;
            zreL[r * ZS + f] = aRe[k3] + bre * zR3[k3];
            zimL[r * ZS + f] = aIm[k3] + bim * zI3[k3];
        }
        __syncthreads();                 // z published for next fwd GEMM
    }

    // final: out = Hn(LDS) @ DFT
    f32x4 fR[3], fI[3];
    #pragma unroll
    for (int q = 0; q < 3; ++q) { fR[q] = (f32x4){0,0,0,0}; fI[q] = (f32x4){0,0,0,0}; }
    #pragma unroll
    for (int ks = 0; ks < 4; ++ks) {
        const int ksa = kq * 4 + ks;
        const int k0 = ksa * 32 + quad * 8;
        short8 hr = *(const short8*)&HreL[(rt * 16 + m) * HST + k0];
        short8 hi = *(const short8*)&HimL[(rt * 16 + m) * HST + k0];
        short8 hin = negbf(hi);
        #pragma unroll
        for (int ft = 0; ft < 3; ++ft) {
            short8 br = *(const short8*)(Dfr + (size_t)((ft * 16 + ksa) * 64 + lane) * 8);
            short8 bi = *(const short8*)(Dfi + (size_t)((ft * 16 + ksa) * 64 + lane) * 8);
            fR[ft] = MFMA(hr, br, fR[ft]);
            fR[ft] = MFMA(hin, bi, fR[ft]);
            fI[ft] = MFMA(hr, bi, fI[ft]);
            fI[ft] = MFMA(hi, br, fI[ft]);
        }
    }
    #pragma unroll
    for (int ft = 0; ft < 3; ++ft) {
        #pragma unroll
        for (int reg = 0; reg < 4; ++reg) {
            pR[((wave * 3 + ft) * 16 + quad * 4 + reg) * 17 + m] = fR[ft][reg];
            pI[((wave * 3 + ft) * 16 + quad * 4 + reg) * 17 + m] = fI[ft][reg];
        }
    }
    __syncthreads();
    float2* out2 = (float2*)out;
    #pragma unroll
    for (int k3 = 0; k3 < 3; ++k3) {
        int j = tid + k3 * THR;
        int r = j / 48, f = j - r * 48;
        int rt2 = r >> 4, lr = r & 15, ft = f >> 4, c = f & 15;
        float hRv = 0.f, hIv = 0.f;
        #pragma unroll
        for (int q = 0; q < 4; ++q) {
            hRv += pR[(((rt2 * 4 + q) * 3 + ft) * 16 + lr) * 17 + c];
            hIv += pI[(((rt2 * 4 + q) * 3 + ft) * 16 + lr) * 17 + c];
        }
        out2[(row0 + r) * 48 + f] = make_float2(hRv, hIv);
    }
}

extern "C" void kernel_launch(void* const* d_in, const int* in_sizes, int n_in,
                              void* d_out, int out_size, void* d_ws, size_t ws_size,
                              hipStream_t stream) {
    (void)in_sizes; (void)n_in; (void)out_size; (void)ws_size;
    const float* u  = (const float*)d_in[0];
    const float* Ar = (const float*)d_in[1];
    const float* Ai = (const float*)d_in[2];
    const float* th = (const float*)d_in[3];
    const float* Dr = (const float*)d_in[4];
    const float* Di = (const float*)d_in[5];
    float* out = (float*)d_out;

    char* p = (char*)d_ws;
    auto alloc = [&](size_t bytes) -> char* {
        char* r = p;
        p += (bytes + 255) & ~(size_t)255;
        return r;
    };
    uint_t*   syncbuf = (uint_t*)alloc((size_t)SYNC_DW * 4);
    ushort_t* Afr = (ushort_t*)alloc((size_t)L_ * 32768 * 2);
    ushort_t* Afi = (ushort_t*)alloc((size_t)L_ * 32768 * 2);
    ushort_t* Atr = (ushort_t*)alloc((size_t)L_ * 24576 * 2);
    ushort_t* Ati = (ushort_t*)alloc((size_t)L_ * 24576 * 2);
    ushort_t* Dfr = (ushort_t*)alloc((size_t)24576 * 2);
    ushort_t* Dfi = (ushort_t*)alloc((size_t)24576 * 2);

    k_pre<<<512, 256, 0, stream>>>(Ar, Ai, Dr, Di, Afr, Afi, Atr, Ati, Dfr, Dfi, syncbuf);

    const uint_t lds_bytes = 132608;
    hipFuncSetAttribute((const void*)k_lamp,
                        hipFuncAttributeMaxDynamicSharedMemorySize, (int)lds_bytes);
    // Regular (non-cooperative) launch: 256 blocks at 132.6 KB LDS = 1 block/CU
    // on 256 CUs -> all blocks co-resident by capacity; custom barrier is safe.
    k_lamp<<<dim3(NBLK), dim3(THR), lds_bytes, stream>>>(
        u, Afr, Afi, Atr, Ati, Dfr, Dfi, th, syncbuf, out);
}